// Round 3
// baseline (117.189 us; speedup 1.0000x reference)
//
#include <hip/hip_runtime.h>
#include <math.h>

#define NUM_BINS 15
#define FL_EPS 1e-20f

// Fused AdaFocal loss, R1 structure (known-good 5.3 TB/s) + last-block reduce.
//  - one wave (64 lanes) per row; row held in NAMED float4 registers
//    (no arrays / no lambdas: R2 showed the allocator demotes pipelined
//    register arrays to scratch -> 3x regression)
//  - max and sum(exp) via 6-step shfl_xor butterflies
//  - inactive slots filled with -INF so __expf() contributes exactly 0
//  - powf replaced by __expf(gm * __logf(base)); base in [eps, 2]
//  - grid sum fused via last-block-done ticket; partials reduced in fixed
//    index order -> deterministic
__global__ __launch_bounds__(256) void adafocal_fused(
    const float* __restrict__ input, const int* __restrict__ target,
    const float* __restrict__ gammas, float* __restrict__ out,
    unsigned int* __restrict__ counter, float* __restrict__ partial,
    int N, int C)
{
    const int lane        = threadIdx.x & 63;
    const int waveInBlock = threadIdx.x >> 6;
    const int globalWave  = blockIdx.x * 4 + waveInBlock;
    const int totalWaves  = gridDim.x * 4;
    const int nvec = C >> 2;      // 250 for C=1000
    const int tail = C & 3;       // 0 for C=1000

    const float NEG = -INFINITY;
    float acc = 0.0f;

    for (int row = globalWave; row < N; row += totalWaves) {
        const float* rowp = input + (size_t)row * (size_t)C;
        const float4* rp4 = reinterpret_cast<const float4*>(rowp);

        const int j0 = lane, j1 = lane + 64, j2 = lane + 128, j3 = lane + 192;
        float4 v0 = (j0 < nvec) ? rp4[j0] : make_float4(NEG, NEG, NEG, NEG);
        float4 v1 = (j1 < nvec) ? rp4[j1] : make_float4(NEG, NEG, NEG, NEG);
        float4 v2 = (j2 < nvec) ? rp4[j2] : make_float4(NEG, NEG, NEG, NEG);
        float4 v3 = (j3 < nvec) ? rp4[j3] : make_float4(NEG, NEG, NEG, NEG);
        float  tl = (lane < tail) ? rowp[(nvec << 2) + lane] : NEG;

        const int t  = target[row];   // wave-uniform
        const float xt = rowp[t];     // issued alongside row loads

        // ---- max ----
        float mx = tl;
        mx = fmaxf(mx, fmaxf(fmaxf(v0.x, v0.y), fmaxf(v0.z, v0.w)));
        mx = fmaxf(mx, fmaxf(fmaxf(v1.x, v1.y), fmaxf(v1.z, v1.w)));
        mx = fmaxf(mx, fmaxf(fmaxf(v2.x, v2.y), fmaxf(v2.z, v2.w)));
        mx = fmaxf(mx, fmaxf(fmaxf(v3.x, v3.y), fmaxf(v3.z, v3.w)));
        #pragma unroll
        for (int off = 32; off >= 1; off >>= 1)
            mx = fmaxf(mx, __shfl_xor(mx, off, 64));

        // ---- sum of exp(x - max) ----
        float s = __expf(tl - mx);    // 0 when tl == -INF
        s += __expf(v0.x - mx) + __expf(v0.y - mx) + __expf(v0.z - mx) + __expf(v0.w - mx);
        s += __expf(v1.x - mx) + __expf(v1.y - mx) + __expf(v1.z - mx) + __expf(v1.w - mx);
        s += __expf(v2.x - mx) + __expf(v2.y - mx) + __expf(v2.z - mx) + __expf(v2.w - mx);
        s += __expf(v3.x - mx) + __expf(v3.y - mx) + __expf(v3.z - mx) + __expf(v3.w - mx);
        #pragma unroll
        for (int off = 32; off >= 1; off >>= 1)
            s += __shfl_xor(s, off, 64);

        // ---- scalar epilogue on lane 0 ----
        if (lane == 0) {
            float logZ  = mx + __logf(s);
            float logpt = xt - logZ;
            float pt    = __expf(logpt);
            int bin = (int)(pt * (float)NUM_BINS);
            bin = min(max(bin, 0), NUM_BINS - 1);
            float g  = gammas[bin];
            float gs = (g > 0.0f) ? 1.0f : ((g < 0.0f) ? -1.0f : 0.0f);
            float base = 1.0f - gs * pt + FL_EPS;       // in [eps, 2]
            acc += -__expf(fabsf(g) * __logf(base)) * logpt;
        }
    }

    // ---- block reduce + last-block-done grid reduce ----
    __shared__ float waveSum[4];
    __shared__ bool  amLast;
    if (lane == 0) waveSum[waveInBlock] = acc;
    __syncthreads();
    if (threadIdx.x == 0) {
        float bsum = waveSum[0] + waveSum[1] + waveSum[2] + waveSum[3];
        partial[blockIdx.x] = bsum;
        __threadfence();                               // release partial
        unsigned int ticket = atomicAdd(counter, 1u);  // device scope
        amLast = (ticket == (unsigned int)gridDim.x - 1u);
    }
    __syncthreads();
    if (amLast) {
        __threadfence();                               // acquire partials
        float s = 0.0f;
        for (int i = threadIdx.x; i < gridDim.x; i += 256) s += partial[i];
        #pragma unroll
        for (int off = 32; off >= 1; off >>= 1)
            s += __shfl_xor(s, off, 64);
        if (lane == 0) waveSum[waveInBlock] = s;
        __syncthreads();
        if (threadIdx.x == 0)
            out[0] = waveSum[0] + waveSum[1] + waveSum[2] + waveSum[3];
    }
}

extern "C" void kernel_launch(void* const* d_in, const int* in_sizes, int n_in,
                              void* d_out, int out_size, void* d_ws, size_t ws_size,
                              hipStream_t stream) {
    const float* input  = (const float*)d_in[0];
    const int*   target = (const int*)d_in[1];
    const float* gammas = (const float*)d_in[2];
    float* out = (float*)d_out;

    const int N = in_sizes[1];             // 65536 rows
    const int C = in_sizes[0] / N;         // 1000 classes
    const int BLOCKS = 2048;               // 8 blocks/CU nominal

    unsigned int* counter = (unsigned int*)d_ws;               // 1 u32
    float*        partial = (float*)((char*)d_ws + 64);        // 2048 floats

    hipMemsetAsync(d_ws, 0, 64, stream);   // zero ticket counter each call
    adafocal_fused<<<BLOCKS, 256, 0, stream>>>(input, target, gammas, out,
                                               counter, partial, N, C);
}

// Round 4
// 71.518 us; speedup vs baseline: 1.6386x; 1.6386x over previous
//
#include <hip/hip_runtime.h>
#include <math.h>

#define NUM_BINS 15
#define FL_EPS 1e-20f

// AdaFocal loss, two-kernel structure (R1, proven 54.7us) + 2-deep row
// pipeline in stage1.
//  - R2/R3 lesson: the fused last-block-done tail (2048 same-address
//    device atomics + per-block threadfence L2 writebacks) cost ~60us.
//    Reverted to the cheap stage2 kernel (~4us).
//  - Pipeline uses NAMED float4 locals + macro-expanded straight-line code
//    (rule #20: arrays/lambdas got demoted to scratch in R2).
//  - One wave per row; max & sum(exp) via 6-step shfl_xor butterflies;
//    next row's 4KB of loads + target-logit chain fly under the current
//    row's butterflies/exp chain.
//  - powf -> __expf(gm * __logf(base)), base in [eps, 2].
__global__ __launch_bounds__(256) void adafocal_stage1(
    const float* __restrict__ input, const int* __restrict__ target,
    const float* __restrict__ gammas, float* __restrict__ partial,
    int N, int C)
{
    const int lane        = threadIdx.x & 63;
    const int waveInBlock = threadIdx.x >> 6;
    const int globalWave  = blockIdx.x * 4 + waveInBlock;
    const int stride      = gridDim.x * 4;
    const int nvec = C >> 2;      // 250 for C=1000
    const int tail = C & 3;       // 0 for C=1000
    const float NEG = -INFINITY;
    const float4 negf4 = make_float4(NEG, NEG, NEG, NEG);
    const int j0 = lane, j1 = lane + 64, j2 = lane + 128, j3 = lane + 192;

    float acc = 0.0f;

#define LOADROW(V0,V1,V2,V3,TL,XT,ROW) do {                                   \
    const float* rowp_ = input + (size_t)(ROW) * (size_t)C;                   \
    const float4* rp4_ = reinterpret_cast<const float4*>(rowp_);              \
    V0 = (j0 < nvec) ? rp4_[j0] : negf4;                                      \
    V1 = (j1 < nvec) ? rp4_[j1] : negf4;                                      \
    V2 = (j2 < nvec) ? rp4_[j2] : negf4;                                      \
    V3 = (j3 < nvec) ? rp4_[j3] : negf4;                                      \
    TL = (lane < tail) ? rowp_[(nvec << 2) + lane] : NEG;                     \
    XT = rowp_[target[(ROW)]];  /* wave-uniform broadcast load */             \
} while (0)

#define COMPUTEROW(V0,V1,V2,V3,TL,XT) do {                                    \
    float mx_ = TL;                                                           \
    mx_ = fmaxf(mx_, fmaxf(fmaxf(V0.x, V0.y), fmaxf(V0.z, V0.w)));            \
    mx_ = fmaxf(mx_, fmaxf(fmaxf(V1.x, V1.y), fmaxf(V1.z, V1.w)));            \
    mx_ = fmaxf(mx_, fmaxf(fmaxf(V2.x, V2.y), fmaxf(V2.z, V2.w)));            \
    mx_ = fmaxf(mx_, fmaxf(fmaxf(V3.x, V3.y), fmaxf(V3.z, V3.w)));            \
    _Pragma("unroll")                                                         \
    for (int off_ = 32; off_ >= 1; off_ >>= 1)                                \
        mx_ = fmaxf(mx_, __shfl_xor(mx_, off_, 64));                          \
    float s_ = __expf(TL - mx_);  /* 0 when TL == -INF */                     \
    s_ += __expf(V0.x - mx_) + __expf(V0.y - mx_)                             \
        + __expf(V0.z - mx_) + __expf(V0.w - mx_);                            \
    s_ += __expf(V1.x - mx_) + __expf(V1.y - mx_)                             \
        + __expf(V1.z - mx_) + __expf(V1.w - mx_);                            \
    s_ += __expf(V2.x - mx_) + __expf(V2.y - mx_)                             \
        + __expf(V2.z - mx_) + __expf(V2.w - mx_);                            \
    s_ += __expf(V3.x - mx_) + __expf(V3.y - mx_)                             \
        + __expf(V3.z - mx_) + __expf(V3.w - mx_);                            \
    _Pragma("unroll")                                                         \
    for (int off_ = 32; off_ >= 1; off_ >>= 1)                                \
        s_ += __shfl_xor(s_, off_, 64);                                       \
    if (lane == 0) {                                                          \
        float logZ_  = mx_ + __logf(s_);                                      \
        float logpt_ = XT - logZ_;                                            \
        float pt_    = __expf(logpt_);                                        \
        int bin_ = (int)(pt_ * (float)NUM_BINS);                              \
        bin_ = min(max(bin_, 0), NUM_BINS - 1);                               \
        float g_  = gammas[bin_];                                             \
        float gs_ = (g_ > 0.0f) ? 1.0f : ((g_ < 0.0f) ? -1.0f : 0.0f);        \
        float base_ = 1.0f - gs_ * pt_ + FL_EPS;   /* in [eps, 2] */          \
        acc += -__expf(fabsf(g_) * __logf(base_)) * logpt_;                   \
    }                                                                         \
} while (0)

    float4 a0, a1, a2, a3, b0, b1, b2, b3;
    float  ta, xa, tb, xb;

    int row = globalWave;
    if (row < N) {
        LOADROW(a0,a1,a2,a3,ta,xa,row);
        for (;;) {
            int nr = row + stride;
            if (nr < N) {
                LOADROW(b0,b1,b2,b3,tb,xb,nr);     // B flies under A's reduce
                COMPUTEROW(a0,a1,a2,a3,ta,xa);
                row = nr;
                nr = row + stride;
                if (nr < N) {
                    LOADROW(a0,a1,a2,a3,ta,xa,nr); // next A under B's reduce
                    COMPUTEROW(b0,b1,b2,b3,tb,xb);
                    row = nr;
                } else {
                    COMPUTEROW(b0,b1,b2,b3,tb,xb);
                    break;
                }
            } else {
                COMPUTEROW(a0,a1,a2,a3,ta,xa);
                break;
            }
        }
    }
#undef LOADROW
#undef COMPUTEROW

    __shared__ float waveSum[4];
    if (lane == 0) waveSum[waveInBlock] = acc;
    __syncthreads();
    if (threadIdx.x == 0)
        partial[blockIdx.x] = waveSum[0] + waveSum[1] + waveSum[2] + waveSum[3];
}

// Stage 2: one block reduces the 2048 block-partials in fixed index order.
__global__ __launch_bounds__(256) void adafocal_stage2(
    const float* __restrict__ partial, int n, float* __restrict__ out)
{
    float s = 0.0f;
    for (int i = threadIdx.x; i < n; i += 256) s += partial[i];
    #pragma unroll
    for (int off = 32; off >= 1; off >>= 1)
        s += __shfl_xor(s, off, 64);
    __shared__ float lds[4];
    if ((threadIdx.x & 63) == 0) lds[threadIdx.x >> 6] = s;
    __syncthreads();
    if (threadIdx.x == 0) out[0] = lds[0] + lds[1] + lds[2] + lds[3];
}

extern "C" void kernel_launch(void* const* d_in, const int* in_sizes, int n_in,
                              void* d_out, int out_size, void* d_ws, size_t ws_size,
                              hipStream_t stream) {
    const float* input  = (const float*)d_in[0];
    const int*   target = (const int*)d_in[1];
    const float* gammas = (const float*)d_in[2];
    float* out = (float*)d_out;

    const int N = in_sizes[1];             // 65536 rows
    const int C = in_sizes[0] / N;         // 1000 classes
    const int BLOCKS = 2048;               // 8 blocks/CU nominal

    float* partial = (float*)d_ws;         // 2048 floats scratch

    adafocal_stage1<<<BLOCKS, 256, 0, stream>>>(input, target, gammas, partial, N, C);
    adafocal_stage2<<<1, 256, 0, stream>>>(partial, BLOCKS, out);
}